// Round 2
// baseline (116.008 us; speedup 1.0000x reference)
//
#include <hip/hip_runtime.h>
#include <cmath>

#define EMBED   1024
#define EPB     8
#define NB      64
#define KTOP    2

// ---------------------------------------------------------------------------
// Kernel 1: reciprocal L2 norms of the 512 expert-key rows.
// ---------------------------------------------------------------------------
__global__ void key_rnorm_kernel(const float* __restrict__ ek,
                                 float* __restrict__ rnorm, int nrows) {
    int wave = (int)((blockIdx.x * blockDim.x + threadIdx.x) >> 6);
    int lane = threadIdx.x & 63;
    if (wave >= nrows) return;
    const float4* row = (const float4*)(ek + (size_t)wave * EMBED);
    float s = 0.f;
#pragma unroll
    for (int c = 0; c < 4; ++c) {
        float4 v = row[c * 64 + lane];
        s += v.x * v.x + v.y * v.y + v.z * v.z + v.w * v.w;
    }
#pragma unroll
    for (int off = 32; off; off >>= 1) s += __shfl_xor(s, off, 64);
    if (lane == 0) rnorm[wave] = 1.0f / fmaxf(sqrtf(s), 1e-12f);
}

// ---------------------------------------------------------------------------
// Kernel 2: 8 tokens per wave, 8 lanes per token.
// Lane (g,s): token = waveBase+g, slice s covers float4 indices {i : i%8==s}
// of the 256-float4 row (contiguous 128B runs per 8-lane group per step).
// 3-step intra-group butterfly (vs 6-step full-wave) reduces 9 values;
// 8 epilogues run concurrently on the s==0 lanes.
// ---------------------------------------------------------------------------
__global__ __launch_bounds__(256) void router_kernel(
        const float* __restrict__ h,
        const int*   __restrict__ op_id,
        const float* __restrict__ ek,
        const float* __restrict__ rk,
        float* __restrict__ out_gid,
        float* __restrict__ out_w,
        int ntok) {
    int lane  = threadIdx.x & 63;
    int waveB = threadIdx.x >> 6;                 // wave in block (0..3)
    int g     = lane >> 3;                        // token group within wave
    int s     = lane & 7;                         // slice within token
    int t     = (blockIdx.x * 4 + waveB) * 8 + g; // token id
    if (t >= ntok) return;

    int b = op_id[t];
    b = min(max(b, 0), NB - 1);

    const float4* h4 = (const float4*)h  + (size_t)t * 256;
    const float4* k4 = (const float4*)ek + (size_t)b * (EPB * 256);

    float dot[EPB] = {0.f,0.f,0.f,0.f,0.f,0.f,0.f,0.f};
    float hh = 0.f;

#pragma unroll
    for (int c = 0; c < 4; ++c) {                 // 4 chunks of 64 float4
        float4 hv[8];
#pragma unroll
        for (int j = 0; j < 8; ++j)
            hv[j] = h4[c * 64 + j * 8 + s];
#pragma unroll
        for (int j = 0; j < 8; ++j)
            hh += hv[j].x * hv[j].x + hv[j].y * hv[j].y +
                  hv[j].z * hv[j].z + hv[j].w * hv[j].w;

#pragma unroll
        for (int e = 0; e < EPB; ++e) {
            const float4* ke = k4 + e * 256 + c * 64 + s;
            float4 kv[8];
#pragma unroll
            for (int j = 0; j < 8; ++j) kv[j] = ke[j * 8];
            float d = dot[e];
#pragma unroll
            for (int j = 0; j < 8; ++j)
                d += hv[j].x * kv[j].x + hv[j].y * kv[j].y +
                     hv[j].z * kv[j].z + hv[j].w * kv[j].w;
            dot[e] = d;
        }
    }

    // 3-step butterfly within the 8-lane group (masks 1,2,4 stay in-group)
#pragma unroll
    for (int off = 1; off < 8; off <<= 1) {
        hh += __shfl_xor(hh, off, 64);
#pragma unroll
        for (int e = 0; e < EPB; ++e) dot[e] += __shfl_xor(dot[e], off, 64);
    }

    if (s == 0) {
        float rh = 1.0f / fmaxf(sqrtf(hh), 1e-12f);
        float sc[EPB];
        float m = -1e30f;
#pragma unroll
        for (int e = 0; e < EPB; ++e) {
            sc[e] = dot[e] * rh * rk[b * EPB + e];   // TAU = 1.0
            m = fmaxf(m, sc[e]);
        }
        float ex[EPB];
        float Z = 0.f;
#pragma unroll
        for (int e = 0; e < EPB; ++e) { ex[e] = expf(sc[e] - m); Z += ex[e]; }

        // top-2, lowest-index tie-break (strict >)
        int i1 = 0;
#pragma unroll
        for (int e = 1; e < EPB; ++e) if (ex[e] > ex[i1]) i1 = e;
        int i2 = (i1 == 0) ? 1 : 0;
#pragma unroll
        for (int e = 0; e < EPB; ++e)
            if (e != i1 && ex[e] > ex[i2]) i2 = e;

        float p1 = ex[i1] / Z;
        float p2 = ex[i2] / Z;
        float wsum = p1 + p2 + 1e-9f;

        out_gid[(size_t)t * KTOP + 0] = (float)(b * EPB + i1);
        out_gid[(size_t)t * KTOP + 1] = (float)(b * EPB + i2);
        out_w  [(size_t)t * KTOP + 0] = p1 / wsum;
        out_w  [(size_t)t * KTOP + 1] = p2 / wsum;
    }
}

extern "C" void kernel_launch(void* const* d_in, const int* in_sizes, int n_in,
                              void* d_out, int out_size, void* d_ws, size_t ws_size,
                              hipStream_t stream) {
    const float* h     = (const float*)d_in[0];
    const int*   op_id = (const int*)  d_in[1];
    const float* ek    = (const float*)d_in[2];

    int ntok  = in_sizes[1];           // B*T tokens
    int nrows = NB * EPB;              // 512 key rows

    float* rk      = (float*)d_ws;
    float* out_gid = (float*)d_out;
    float* out_w   = out_gid + (size_t)ntok * KTOP;

    int blocks1 = (nrows * 64 + 255) / 256;
    key_rnorm_kernel<<<blocks1, 256, 0, stream>>>(ek, rk, nrows);

    // 32 tokens per 256-thread block (4 waves x 8 tokens)
    int blocks2 = (ntok + 31) / 32;
    router_kernel<<<blocks2, 256, 0, stream>>>(h, op_id, ek, rk, out_gid, out_w, ntok);
}